// Round 3
// baseline (859.642 us; speedup 1.0000x reference)
//
#include <hip/hip_runtime.h>
#include <hip/hip_bf16.h>
#include <stdio.h>

// BNBQuantizedLinear: out = x @ dequant(w)^T + bias
// x [8192,4096] f32, w [11008,4096] f32 (group-128 affine fake-quant), out f32.
// Round 3: 256x256 tile, BK=32, 4-deep K-tile ring, ONE barrier + ONE counted
// vmcnt(8) per K-tile (hazard analysis: 4-buffer ring makes mid-tile barriers
// redundant); stage issued at tile top; 12 ds_read_b128 + 32 MFMA in one
// compiler-scheduled region under setprio. T1 XCD swizzle + T2 source-side
// XOR swizzle retained (bank conflicts measured 0).

typedef unsigned short u16;
typedef __attribute__((ext_vector_type(8))) short short8;
typedef __attribute__((ext_vector_type(8))) unsigned short ushort8;
typedef __attribute__((ext_vector_type(4))) float f32x4;

constexpr int Mdim = 8192;
constexpr int Ndim = 11008;
constexpr int Kdim = 4096;

#define BK 32
#define NTILES 128          // Kdim / BK
#define TILE_ELEMS 8192     // 256 rows * 32 cols u16 per K-tile buffer (16 KB)

__device__ __forceinline__ u16 f2bf(float f) {
  union { float f; unsigned u; } c; c.f = f;
  unsigned r = c.u + 0x7FFFu + ((c.u >> 16) & 1u);  // RTNE
  return (u16)(r >> 16);
}

// ---------------- kernel 1: group-dequant weight -> bf16 ----------------
__global__ __launch_bounds__(256) void k_dequant_w(const float* __restrict__ w,
                                                   u16* __restrict__ wb) {
  const int lane = threadIdx.x & 63;
  const long g = (long)blockIdx.x * 4 + (threadIdx.x >> 6);
  const long base = g * 128 + lane * 2;
  const float2 v = *(const float2*)(w + base);
  float mn = fminf(v.x, v.y), mx = fmaxf(v.x, v.y);
#pragma unroll
  for (int off = 32; off > 0; off >>= 1) {
    mn = fminf(mn, __shfl_xor(mn, off));
    mx = fmaxf(mx, __shfl_xor(mx, off));
  }
  const float scale = (mx - mn) / 15.0f;
  const float zp = -mn / scale;
  const u16 o0 = f2bf((v.x - zp) * scale);
  const u16 o1 = f2bf((v.y - zp) * scale);
  *(unsigned*)(wb + base) = (unsigned)o0 | ((unsigned)o1 << 16);
}

// ---------------- kernel 2: x f32 -> bf16 ----------------
__global__ __launch_bounds__(256) void k_cvt_x(const float* __restrict__ x,
                                               u16* __restrict__ xb) {
  const long i = ((long)blockIdx.x * 256 + threadIdx.x) * 8;
  const float4 v0 = *(const float4*)(x + i);
  const float4 v1 = *(const float4*)(x + i + 4);
  ushort8 o;
  o[0] = f2bf(v0.x); o[1] = f2bf(v0.y); o[2] = f2bf(v0.z); o[3] = f2bf(v0.w);
  o[4] = f2bf(v1.x); o[5] = f2bf(v1.y); o[6] = f2bf(v1.z); o[7] = f2bf(v1.w);
  *(ushort8*)(xb + i) = o;
}

// ---------------- kernel 3: deep-pipelined 256x256 bf16 GEMM ----------------
__device__ __forceinline__ void async_ld16(const u16* g, u16* l) {
  __builtin_amdgcn_global_load_lds(
      (const __attribute__((address_space(1))) void*)g,
      (__attribute__((address_space(3))) void*)l, 16, 0, 0);
}

// LDS per K-tile buffer: [256 rows][4 slots of 16B], linear dest for
// global_load_lds; SOURCE pre-swizzled with slot ^= (row>>1)&3 (involution),
// ds_read applies the same XOR -> 8 lanes per bank-quad uniform = conflict-free.

__global__ __launch_bounds__(512, 2) void k_gemm(const u16* __restrict__ A,
                                                 const u16* __restrict__ B,
                                                 const float* __restrict__ bias,
                                                 float* __restrict__ C) {
  __shared__ u16 As[4 * TILE_ELEMS];   // 64 KB
  __shared__ u16 Bs[4 * TILE_ELEMS];   // 64 KB

  const int t = threadIdx.x;
  const int wave = t >> 6;        // 0..7
  const int lane = t & 63;
  const int wm = wave >> 2;       // 2(M) x 4(N) wave grid; wave owns 128x64 out
  const int wn = wave & 3;
  const int r  = lane & 15;
  const int kg = lane >> 4;
  const int slot = kg ^ ((r >> 1) & 3);

  // bijective XCD swizzle: 1376 workgroups = 8 XCDs x 172
  const int bid = blockIdx.x;
  const int wg = (bid & 7) * 172 + (bid >> 3);
  const int by = wg / 43;
  const int bx = wg % 43;
  const long bm0 = (long)by * 256;
  const long bn0 = (long)bx * 256;

  // staging: one issue = 512 thr x 16B = 8 KB = 128 rows. 2 issues per matrix.
  const int s_row  = t >> 2;
  const int s_slot = (t & 3) ^ ((t >> 3) & 3);
  const u16* a_src = A + (bm0 + s_row) * Kdim + s_slot * 8;
  const u16* b_src = B + (bn0 + s_row) * Kdim + s_slot * 8;
  const int st_off = wave * 512;

  const int a_roff = (wm * 128 + r) * 32 + slot * 8;  // + mf*512
  const int b_roff = (wn * 64  + r) * 32 + slot * 8;  // + nf*512

  f32x4 acc[8][4] = {};

#define STAGE_A(TAU, BUF) do {                                    \
    const u16* g_ = a_src + (size_t)(TAU) * 32;                   \
    u16* l_ = As + (BUF) * TILE_ELEMS + st_off;                   \
    async_ld16(g_, l_);                                           \
    async_ld16(g_ + (size_t)128 * Kdim, l_ + 4096);               \
  } while (0)
#define STAGE_B(TAU, BUF) do {                                    \
    const u16* g_ = b_src + (size_t)(TAU) * 32;                   \
    u16* l_ = Bs + (BUF) * TILE_ELEMS + st_off;                   \
    async_ld16(g_, l_);                                           \
    async_ld16(g_ + (size_t)128 * Kdim, l_ + 4096);               \
  } while (0)

  // prologue: stage tiles 0,1,2 (12 loads in flight), land tile 0
  STAGE_A(0, 0); STAGE_B(0, 0);
  STAGE_A(1, 1); STAGE_B(1, 1);
  STAGE_A(2, 2); STAGE_B(2, 2);
  asm volatile("s_waitcnt vmcnt(8)" ::: "memory");
  __builtin_amdgcn_s_barrier();

  // One K-tile: stage tau+3, 12 ds_read_b128, 32 MFMA (compiler-scheduled),
  // counted vmcnt (drains tau+1's 4 loads), ONE barrier.
  // Hazards: staging into buf (tau+3)&3 = (tau-1)&3 is safe because all waves'
  // reads of tau-1 completed (lgkm-drained before their MFMAs) before barrier
  // B_{tau-1}, which every wave passed before entering tile tau.
#define KTILE(TAU, BUF, DO_STAGE, VMSTMT) do {                               \
    if (DO_STAGE) { STAGE_A((TAU) + 3, ((BUF) + 3) & 3);                     \
                    STAGE_B((TAU) + 3, ((BUF) + 3) & 3); }                   \
    const u16* Ab_ = As + (BUF) * TILE_ELEMS;                                \
    const u16* Bb_ = Bs + (BUF) * TILE_ELEMS;                                \
    short8 af[8], bfr[4];                                                    \
    _Pragma("unroll")                                                        \
    for (int mf = 0; mf < 8; ++mf) af[mf] = *(const short8*)&Ab_[a_roff + mf*512]; \
    _Pragma("unroll")                                                        \
    for (int nf = 0; nf < 4; ++nf) bfr[nf] = *(const short8*)&Bb_[b_roff + nf*512]; \
    __builtin_amdgcn_s_setprio(1);                                           \
    _Pragma("unroll")                                                        \
    for (int mf = 0; mf < 8; ++mf)                                           \
      _Pragma("unroll")                                                      \
      for (int nf = 0; nf < 4; ++nf)                                         \
        acc[mf][nf] = __builtin_amdgcn_mfma_f32_16x16x32_bf16(af[mf], bfr[nf], acc[mf][nf], 0, 0, 0); \
    __builtin_amdgcn_s_setprio(0);                                           \
    VMSTMT;                                                                  \
    __builtin_amdgcn_s_barrier();                                            \
  } while (0)

#define VM8 asm volatile("s_waitcnt vmcnt(8)" ::: "memory")
#define VM4 asm volatile("s_waitcnt vmcnt(4)" ::: "memory")
#define VM0 asm volatile("s_waitcnt vmcnt(0)" ::: "memory")

  for (int tau = 0; tau < NTILES - 4; tau += 4) {
    KTILE(tau + 0, 0, 1, VM8);
    KTILE(tau + 1, 1, 1, VM8);
    KTILE(tau + 2, 2, 1, VM8);
    KTILE(tau + 3, 3, 1, VM8);
  }
  KTILE(NTILES - 4, 0, 1, VM8);   // stages tile 127
  KTILE(NTILES - 3, 1, 0, VM4);
  KTILE(NTILES - 2, 2, 0, VM0);
  KTILE(NTILES - 1, 3, 0, (void)0);

  // epilogue: C/D layout col = lane&15, row = (lane>>4)*4 + j
#pragma unroll
  for (int nf = 0; nf < 4; ++nf) {
    const long col = bn0 + wn * 64 + nf * 16 + r;
    const float bv = bias[col];
#pragma unroll
    for (int mf = 0; mf < 8; ++mf) {
      const long row0 = bm0 + wm * 128 + mf * 16 + kg * 4;
#pragma unroll
      for (int j = 0; j < 4; ++j)
        C[(row0 + j) * Ndim + col] = acc[mf][nf][j] + bv;
    }
  }
}

extern "C" void kernel_launch(void* const* d_in, const int* in_sizes, int n_in,
                              void* d_out, int out_size, void* d_ws, size_t ws_size,
                              hipStream_t stream) {
  const float* x    = (const float*)d_in[0];
  const float* w    = (const float*)d_in[1];
  const float* bias = (const float*)d_in[2];
  float* out = (float*)d_out;

  const size_t xb_elems = (size_t)Mdim * Kdim;
  const size_t wb_elems = (size_t)Ndim * Kdim;
  const size_t need = (xb_elems + wb_elems) * sizeof(u16);
  if (ws_size < need) {
    fprintf(stderr, "kernel_launch: ws too small (%zu < %zu)\n", ws_size, need);
    return;
  }
  u16* xb = (u16*)d_ws;
  u16* wb = xb + xb_elems;

  k_dequant_w<<<(int)(wb_elems / 128 / 4), 256, 0, stream>>>(w, wb);
  k_cvt_x<<<(int)(xb_elems / (8 * 256)), 256, 0, stream>>>(x, xb);

  k_gemm<<<(Ndim / 256) * (Mdim / 256), 512, 0, stream>>>(xb, wb, bias, out);
}